// Round 6
// baseline (1192.169 us; speedup 1.0000x reference)
//
#include <hip/hip_runtime.h>
#include <math.h>

#define N_NODES 100000
#define N_EDGES 3200000
#define SCAN_NB ((N_NODES + 255) / 256)   // 391

// Two-phase CSR build: 128 dst-range buckets, LDS-resident CSR assembly.
// Degree histogram is derived per-bucket in k_csr (no global atomics anywhere).
#define N_BKT 128
#define NPB 782                           // nodes per bucket (128*782 = 100096 >= N)
#define HALF_NPB 391
#define BKT_CHUNK 2000
#define BKT_NB (N_EDGES / BKT_CHUNK)      // 1600 blocks
#define BKT_LDS_CAP 64                    // per-bucket LDS staging (mean 15.6, P(ovfl)~1e-18)
#define BUCKET_CAP 26624                  // per-bucket global region (mean 25000, +10 sigma)
#define SLICE_CAP 14336                   // LDS csr slice (mean 12512, +16 sigma)

// MLP pass A tiling: 128-node tile, k staged in 4 chunks of <=33
#define TILE_NODES 128
#define KCH 33
#define MLP1_NB ((N_NODES + TILE_NODES - 1) / TILE_NODES)   // 782

// ---------------- CSR build ----------------

__global__ void k_init(int* __restrict__ bcnt) {
    int i = threadIdx.x;
    if (i < N_BKT) bcnt[i] = 0;
}

// Phase 1: single coalesced pass over edges, pure bucketing (no global atomics).
// pack = (dst_local << 17) | src (dloc < 782 -> 10 bits, src < 100000 -> 17 bits).
// LDS-staged, flushed with coalesced NT stores.
__global__ __launch_bounds__(256) void k_bucket(
        const int* __restrict__ src, const int* __restrict__ dst,
        int* __restrict__ bcnt,
        unsigned int* __restrict__ bdata) {
    __shared__ unsigned int buf[N_BKT * BKT_LDS_CAP];   // 32768 B
    __shared__ int lcnt[N_BKT];
    __shared__ int gbase[N_BKT];
    const int t = threadIdx.x;
    if (t < N_BKT) lcnt[t] = 0;
    __syncthreads();

    const int e0 = blockIdx.x * BKT_CHUNK;
    for (int e = e0 + t; e < e0 + BKT_CHUNK; e += 256) {
        int d = __builtin_nontemporal_load(&dst[e]);
        int s = __builtin_nontemporal_load(&src[e]);
        int b = d / NPB;                              // magic-mul (const divisor)
        int dloc = d - b * NPB;
        unsigned int pack = ((unsigned int)dloc << 17) | (unsigned int)s;
        int p = atomicAdd(&lcnt[b], 1);               // LDS atomic
        if (p < BKT_LDS_CAP)                          // defensive clamp (never expected)
            buf[b * BKT_LDS_CAP + p] = pack;
    }
    __syncthreads();
    if (t < N_BKT) {
        int n = min(lcnt[t], BKT_LDS_CAP);
        lcnt[t] = n;
        gbase[t] = atomicAdd(&bcnt[t], n);
    }
    __syncthreads();
    const int wv = t >> 6, ln = t & 63;
    for (int b = wv; b < N_BKT; b += 4) {
        int n = lcnt[b];
        unsigned int* outp = bdata + (size_t)b * BUCKET_CAP + gbase[b];
        for (int i = ln; i < n; i += 64)
            __builtin_nontemporal_store(buf[b * BKT_LDS_CAP + i], &outp[i]);
    }
}

// Exclusive scan of the 128 bucket totals -> row_start of each bucket's first node.
__global__ __launch_bounds__(128) void k_bscan(const int* __restrict__ bcnt,
                                               int* __restrict__ bb) {
    __shared__ int s[128];
    const int t = threadIdx.x;
    int v = bcnt[t];
    s[t] = v;
    __syncthreads();
    for (int off = 1; off < 128; off <<= 1) {
        int a = (t >= off) ? s[t - off] : 0;
        __syncthreads();
        s[t] += a;
        __syncthreads();
    }
    bb[t] = s[t] - v;   // exclusive
    if (t == 127) bb[128] = s[127];
}

// Phase 2: LDS-resident CSR assembly + per-bucket degree derivation.
__global__ __launch_bounds__(512) void k_csr(
        const unsigned int* __restrict__ bdata,
        const int* __restrict__ bcnt,
        const int* __restrict__ bb,
        int* __restrict__ count,
        int* __restrict__ row_start,
        float* __restrict__ dinv,
        int* __restrict__ csr_src) {
    __shared__ int lhist[NPB];
    __shared__ int lrs[NPB];
    __shared__ int lcsr[SLICE_CAP];     // total LDS 63600 B
    const int b = blockIdx.x >> 1;
    const int half = blockIdx.x & 1;
    const int t = threadIdx.x;
    const int total = bcnt[b];
    const int bb_b = bb[b];
    const unsigned int* data = bdata + (size_t)b * BUCKET_CAP;

    for (int i = t; i < NPB; i += 512) lhist[i] = 0;
    __syncthreads();
    for (int i = t; i < total; i += 512) {
        unsigned int pack = __builtin_nontemporal_load(&data[i]);
        atomicAdd(&lhist[pack >> 17], 1);             // no-return LDS atomic
    }
    __syncthreads();
    // exclusive scan lhist -> lrs (wave 0: 13 elems/lane + shfl_up wave scan)
    if (t < 64) {
        int loc[13];
        int s = 0;
#pragma unroll
        for (int k = 0; k < 13; ++k) {
            int idx = t * 13 + k;
            int v = (idx < NPB) ? lhist[idx] : 0;
            loc[k] = v; s += v;
        }
        int run = s;
#pragma unroll
        for (int off = 1; off < 64; off <<= 1) {
            int o = __shfl_up(run, off, 64);
            if (t >= off) run += o;
        }
        int excl = run - s;
#pragma unroll
        for (int k = 0; k < 13; ++k) {
            int idx = t * 13 + k;
            if (idx < NPB) lrs[idx] = excl;
            excl += loc[k];
        }
    }
    __syncthreads();
    // per-node outputs for this half (coalesced)
    const int node_lo = b * NPB + half * HALF_NPB;
    int node_hi = b * NPB + (half ? NPB : HALF_NPB);
    if (node_hi > N_NODES) node_hi = N_NODES;
    const int nn = node_hi - node_lo;
    for (int i = t; i < nn; i += 512) {
        int dloc = half * HALF_NPB + i;
        int c = lhist[dloc];
        count[node_lo + i] = c;
        row_start[node_lo + i] = bb_b + lrs[dloc];
        dinv[node_lo + i] = 1.0f / sqrtf((float)(c + 1));   // deg incl self-loop
    }
    const int slice_off = lrs[half * HALF_NPB];
    const int slice_len = half ? (total - slice_off) : lrs[HALF_NPB];
    __syncthreads();   // lhist reads done -> safe to reuse as cursors
    const int dlo = half * HALF_NPB;
    const int dhi = dlo + HALF_NPB;
    for (int i = t; i < HALF_NPB; i += 512)
        lhist[dlo + i] = lrs[dlo + i] - slice_off;    // slice-local cursors
    __syncthreads();
    for (int i = t; i < total; i += 512) {
        unsigned int pack = __builtin_nontemporal_load(&data[i]);
        int dloc = (int)(pack >> 17);
        if (dloc >= dlo && dloc < dhi) {
            int p = atomicAdd(&lhist[dloc], 1);
            if (p < SLICE_CAP)                        // defensive clamp (never expected)
                lcsr[p] = (int)(pack & 0x1FFFFu);
        }
    }
    __syncthreads();
    const int gb = bb_b + slice_off;
    for (int i = t; i < slice_len; i += 512)
        __builtin_nontemporal_store(lcsr[i], &csr_src[gb + i]);
}

// ---------------- MLP pass A: layer 1 (131 -> 64), k-chunked LDS staging ----------------
// 512 threads / 128-node tile: thread quarter (t>>7, wave-uniform) owns 16 of the
// 64 outputs -> 16 accumulators/thread. 782 blocks x 8 waves = 24 waves/CU (~75%
// occupancy; the old 4-wave blocks were grid-starved at 12 waves/CU). x staged per
// k-chunk (128x33 = 16.9 KB). Output feature-major h1T[j][node], coalesced.

__global__ __launch_bounds__(512) void k_mlp1(
        const float* __restrict__ x,
        const float* __restrict__ W1, const float* __restrict__ b1,
        float* __restrict__ h1T) {
    __shared__ float xs[TILE_NODES * KCH];   // 16896 B
    const int t = threadIdx.x;
    const int nl = t & 127;
    const int q_u = __builtin_amdgcn_readfirstlane(t >> 7);  // wave-uniform quarter
    const int nbase = blockIdx.x * TILE_NODES;
    const int node = nbase + nl;

    float a[16];
#pragma unroll
    for (int j = 0; j < 16; ++j) a[j] = b1[q_u * 16 + j];

    for (int kc = 0; kc < 4; ++kc) {
        const int k0 = kc * KCH;
        const int len = (k0 + KCH <= 131) ? KCH : (131 - k0);   // 33,33,33,32
        __syncthreads();
        for (int i = t; i < TILE_NODES * KCH; i += 512) {
            int r = i / KCH;
            int c = i - r * KCH;
            int gr = nbase + r;
            xs[i] = (c < len && gr < N_NODES) ? x[(long)gr * 131 + k0 + c] : 0.0f;
        }
        __syncthreads();
        const float* myrow = xs + nl * KCH;
        for (int kk = 0; kk < len; ++kk) {
            float xk = myrow[kk];
            const float* wr = W1 + (k0 + kk) * 64 + q_u * 16;   // uniform -> s_load
#pragma unroll
            for (int j = 0; j < 16; ++j) a[j] += xk * wr[j];
        }
    }

    if (node < N_NODES) {
#pragma unroll
        for (int j = 0; j < 16; ++j)
            h1T[(q_u * 16 + j) * N_NODES + node] = tanhf(a[j]);
    }
}

// ---------------- MLP pass B: 64 -> 32 -> 16 -> conv-fuse ----------------
// Writes unified layout u[node*16 + j] (one 64 B line per node), dinv-scaled.

__global__ __launch_bounds__(256) void k_mlp2(
        const float* __restrict__ h1T,
        const float* __restrict__ W2, const float* __restrict__ b2,
        const float* __restrict__ W3, const float* __restrict__ b3,
        const float* __restrict__ Wc1,
        const float* __restrict__ dinv,
        float* __restrict__ up) {
    const int node = blockIdx.x * 256 + threadIdx.x;
    if (node >= N_NODES) return;

    float a2[32];
#pragma unroll
    for (int j = 0; j < 32; ++j) a2[j] = b2[j];
    for (int k = 0; k < 64; ++k) {
        float hk = h1T[k * N_NODES + node];           // coalesced
        const float* wr = W2 + k * 32;                // uniform -> s_load
#pragma unroll
        for (int j = 0; j < 32; ++j) a2[j] += hk * wr[j];
    }
#pragma unroll
    for (int j = 0; j < 32; ++j) a2[j] = tanhf(a2[j]);

    float a3[16];
#pragma unroll
    for (int j = 0; j < 16; ++j) a3[j] = b3[j];
#pragma unroll 4
    for (int k = 0; k < 32; ++k) {
        float hk = a2[k];
        const float* wr = W3 + k * 16;
#pragma unroll
        for (int j = 0; j < 16; ++j) a3[j] += hk * wr[j];
    }

    float dv = dinv[node];
    float uo[16];
#pragma unroll
    for (int j = 0; j < 16; ++j) uo[j] = 0.0f;
#pragma unroll 4
    for (int k = 0; k < 16; ++k) {
        float hk = a3[k];
        const float* wr = Wc1 + k * 16;
#pragma unroll
        for (int j = 0; j < 16; ++j) uo[j] += hk * wr[j];
    }
    float4* p = reinterpret_cast<float4*>(up + (long)node * 16);
    float4 v;
    v.x = uo[0] * dv; v.y = uo[1] * dv; v.z = uo[2] * dv; v.w = uo[3] * dv; p[0] = v;
    v.x = uo[4] * dv; v.y = uo[5] * dv; v.z = uo[6] * dv; v.w = uo[7] * dv; p[1] = v;
    v.x = uo[8] * dv; v.y = uo[9] * dv; v.z = uo[10] * dv; v.w = uo[11] * dv; p[2] = v;
    v.x = uo[12] * dv; v.y = uo[13] * dv; v.z = uo[14] * dv; v.w = uo[15] * dv; p[3] = v;
}

// ---------------- Fused aggregation + tanh + 16x16 transform (or classifier) ----------------
// One wave = 2 nodes x 16 features x 2 edge-groups. All 16 features per edge in
// one pass: csr/count/row_start/dinv read ONCE per launch (old half-split read
// them twice), and each gather consumes a full 64 B line (u[node*16+f]).
// Epilogue folds the next layer's h@W (16 shuffles against a preloaded W column)
// so the separate k_trans kernel + hp round-trip disappear. mode 1 = classifier.

__global__ __launch_bounds__(256) void k_agg(
        const float* __restrict__ u,
        const int* __restrict__ row_start,
        const int* __restrict__ count,
        const int* __restrict__ csr_src,
        const float* __restrict__ dinv,
        const float* __restrict__ bias,
        const float* __restrict__ W,      // 16x16 (mode 0) or 16x2 Wcls (mode 1)
        const float* __restrict__ bcls,   // mode 1 only
        float* __restrict__ u_next,       // mode 0 output
        float* __restrict__ out,          // mode 1 output
        int mode) {
    const int wave = threadIdx.x >> 6;
    const int lane = threadIdx.x & 63;
    const int f = lane & 15;
    const int eg = (lane >> 4) & 1;
    const int node = blockIdx.x * 8 + wave * 2 + (lane >> 5);   // 12500*8 = 100000

    const int rs = row_start[node];
    const int cnt = count[node];
    const float dv = dinv[node];
    int cmax = max(cnt, __shfl_xor(cnt, 32, 64));   // wave-uniform loop bound

    float wcol[16];
    if (mode == 0) {
#pragma unroll
        for (int k = 0; k < 16; ++k) wcol[k] = W[k * 16 + f];   // lane's W column
    }

    float acc = 0.0f;
    for (int base = 0; base < cmax; base += 32) {
        int ei2 = rs + base + (lane & 31);
        if (ei2 > N_EDGES - 1) ei2 = N_EDGES - 1;    // tail clamp (guarded below anyway)
        int idx = __builtin_nontemporal_load(&csr_src[ei2]);
#pragma unroll
        for (int k = 0; k < 16; ++k) {
            int e = base + 2 * k + eg;
            int s = __shfl(idx, (lane & 32) + 2 * k + eg, 64);
            if (e < cnt) acc += u[(long)s * 16 + f];
        }
    }
    acc += __shfl_xor(acc, 16, 64);        // sum the 2 edge-groups (both keep total)
    acc += u[(long)node * 16 + f];         // self-loop (u already dinv[src]-scaled)
    float hn = tanhf(dv * acc + bias[f]);

    if (mode == 0) {
        float o = 0.0f;
#pragma unroll
        for (int k = 0; k < 16; ++k) {
            float hk = __shfl(hn, (lane & 32) + k, 64);
            o += hk * wcol[k];
        }
        if (eg == 0) u_next[(long)node * 16 + f] = dv * o;
    } else {
        if (eg == 0) out[200000 + (long)node * 16 + f] = hn;
        float p0 = hn * W[f * 2 + 0];
        float p1 = hn * W[f * 2 + 1];
        p0 += __shfl_xor(p0, 1, 64);  p1 += __shfl_xor(p1, 1, 64);
        p0 += __shfl_xor(p0, 2, 64);  p1 += __shfl_xor(p1, 2, 64);
        p0 += __shfl_xor(p0, 4, 64);  p1 += __shfl_xor(p1, 4, 64);
        p0 += __shfl_xor(p0, 8, 64);  p1 += __shfl_xor(p1, 8, 64);
        if ((lane & 31) == 0) {
            out[(long)node * 2 + 0] = p0 + bcls[0];
            out[(long)node * 2 + 1] = p1 + bcls[1];
        }
    }
}

// ---------------- launch ----------------

extern "C" void kernel_launch(void* const* d_in, const int* in_sizes, int n_in,
                              void* d_out, int out_size, void* d_ws, size_t ws_size,
                              hipStream_t stream) {
    const float* x    = (const float*)d_in[0];
    const int*   ei   = (const int*)d_in[1];
    const float* W1   = (const float*)d_in[2];
    const float* b1   = (const float*)d_in[3];
    const float* W2   = (const float*)d_in[4];
    const float* b2   = (const float*)d_in[5];
    const float* W3   = (const float*)d_in[6];
    const float* b3   = (const float*)d_in[7];
    const float* Wc1  = (const float*)d_in[8];
    const float* bc1  = (const float*)d_in[9];
    const float* Wg   = (const float*)d_in[10];
    const float* bg   = (const float*)d_in[11];
    const float* Wcls = (const float*)d_in[12];
    const float* bcls = (const float*)d_in[13];
    float* out = (float*)d_out;

    const int* src = ei;
    const int* dst = ei + N_EDGES;

    int* count     = (int*)d_ws;
    int* row_start = count + N_NODES;
    float* dinv    = (float*)(row_start + N_NODES);
    int* bcnt      = (int*)(dinv + N_NODES);        // 128 ints
    int* bb        = bcnt + N_BKT;                  // 129 ints (padded to 132)
    int* csr_src   = bb + 132;
    float* u0      = (float*)(csr_src + N_EDGES);   // N*16 floats (6.4 MB), 16B-aligned
    float* u1      = u0 + 16 * N_NODES;             // N*16 floats
    float* h1T     = u1 + 16 * N_NODES;             // 64 * N floats (25.6 MB)
    unsigned int* bdata = (unsigned int*)h1T;       // 13.6 MB, dead before k_mlp1 writes h1T

    k_init<<<1, 128, 0, stream>>>(bcnt);
    k_bucket<<<BKT_NB, 256, 0, stream>>>(src, dst, bcnt, bdata);
    k_bscan<<<1, 128, 0, stream>>>(bcnt, bb);
    k_csr<<<2 * N_BKT, 512, 0, stream>>>(bdata, bcnt, bb, count, row_start, dinv, csr_src);
    k_mlp1<<<MLP1_NB, 512, 0, stream>>>(x, W1, b1, h1T);
    k_mlp2<<<SCAN_NB, 256, 0, stream>>>(h1T, W2, b2, W3, b3, Wc1, dinv, u0);

    float* ucur = u0;
    float* unxt = u1;
    for (int j = 0; j < 10; ++j) {
        const float* bias = (j < 5) ? bc1 : (bg + (long)(j - 5) * 16);
        if (j < 9) {
            const float* Wn = (j < 4) ? Wc1 : (Wg + (long)(j - 4) * 256);
            k_agg<<<12500, 256, 0, stream>>>(ucur, row_start, count, csr_src, dinv,
                                             bias, Wn, nullptr, unxt, nullptr, 0);
            float* tmp = ucur; ucur = unxt; unxt = tmp;
        } else {
            k_agg<<<12500, 256, 0, stream>>>(ucur, row_start, count, csr_src, dinv,
                                             bias, Wcls, bcls, nullptr, out, 1);
        }
    }
}

// Round 7
// 939.363 us; speedup vs baseline: 1.2691x; 1.2691x over previous
//
#include <hip/hip_runtime.h>
#include <math.h>

#define N_NODES 100000
#define N_EDGES 3200000
#define SCAN_NB ((N_NODES + 255) / 256)   // 391

// Two-phase CSR build: 128 dst-range buckets, LDS-resident CSR assembly.
#define N_BKT 128
#define NPB 782                           // nodes per bucket (128*782 = 100096 >= N)
#define HALF_NPB 391
#define BKT_CHUNK 2000
#define BKT_NB (N_EDGES / BKT_CHUNK)      // 1600 blocks
#define BKT_LDS_CAP 64                    // per-bucket LDS staging (mean 15.6, P(ovfl)~1e-18)
#define BUCKET_CAP 26624                  // per-bucket global region (mean 25000, +10 sigma)
#define SLICE_CAP 14336                   // LDS csr slice (mean 12512, +16 sigma)

// MLP pass A tiling: 128-node tile, k staged in 4 chunks of <=33
#define TILE_NODES 128
#define KCH 33
#define MLP1_NB ((N_NODES + TILE_NODES - 1) / TILE_NODES)   // 782

// ---------------- CSR build ----------------

__global__ void k_init(int* __restrict__ bcnt) {
    int i = threadIdx.x;
    if (i < N_BKT) bcnt[i] = 0;
}

// Phase 1: single coalesced pass over edges, pure bucketing (no global atomics).
__global__ __launch_bounds__(256) void k_bucket(
        const int* __restrict__ src, const int* __restrict__ dst,
        int* __restrict__ bcnt,
        unsigned int* __restrict__ bdata) {
    __shared__ unsigned int buf[N_BKT * BKT_LDS_CAP];   // 32768 B
    __shared__ int lcnt[N_BKT];
    __shared__ int gbase[N_BKT];
    const int t = threadIdx.x;
    if (t < N_BKT) lcnt[t] = 0;
    __syncthreads();

    const int e0 = blockIdx.x * BKT_CHUNK;
    for (int e = e0 + t; e < e0 + BKT_CHUNK; e += 256) {
        int d = __builtin_nontemporal_load(&dst[e]);
        int s = __builtin_nontemporal_load(&src[e]);
        int b = d / NPB;                              // magic-mul (const divisor)
        int dloc = d - b * NPB;
        unsigned int pack = ((unsigned int)dloc << 17) | (unsigned int)s;
        int p = atomicAdd(&lcnt[b], 1);               // LDS atomic
        if (p < BKT_LDS_CAP)                          // defensive clamp (never expected)
            buf[b * BKT_LDS_CAP + p] = pack;
    }
    __syncthreads();
    if (t < N_BKT) {
        int n = min(lcnt[t], BKT_LDS_CAP);
        lcnt[t] = n;
        gbase[t] = atomicAdd(&bcnt[t], n);
    }
    __syncthreads();
    const int wv = t >> 6, ln = t & 63;
    for (int b = wv; b < N_BKT; b += 4) {
        int n = lcnt[b];
        unsigned int* outp = bdata + (size_t)b * BUCKET_CAP + gbase[b];
        for (int i = ln; i < n; i += 64)
            __builtin_nontemporal_store(buf[b * BKT_LDS_CAP + i], &outp[i]);
    }
}

// Exclusive scan of the 128 bucket totals -> row_start of each bucket's first node.
__global__ __launch_bounds__(128) void k_bscan(const int* __restrict__ bcnt,
                                               int* __restrict__ bb) {
    __shared__ int s[128];
    const int t = threadIdx.x;
    int v = bcnt[t];
    s[t] = v;
    __syncthreads();
    for (int off = 1; off < 128; off <<= 1) {
        int a = (t >= off) ? s[t - off] : 0;
        __syncthreads();
        s[t] += a;
        __syncthreads();
    }
    bb[t] = s[t] - v;   // exclusive
    if (t == 127) bb[128] = s[127];
}

// Phase 2: LDS-resident CSR assembly + per-bucket degree derivation.
__global__ __launch_bounds__(512) void k_csr(
        const unsigned int* __restrict__ bdata,
        const int* __restrict__ bcnt,
        const int* __restrict__ bb,
        int* __restrict__ count,
        int* __restrict__ row_start,
        float* __restrict__ dinv,
        int* __restrict__ csr_src) {
    __shared__ int lhist[NPB];
    __shared__ int lrs[NPB];
    __shared__ int lcsr[SLICE_CAP];     // total LDS 63600 B
    const int b = blockIdx.x >> 1;
    const int half = blockIdx.x & 1;
    const int t = threadIdx.x;
    const int total = bcnt[b];
    const int bb_b = bb[b];
    const unsigned int* data = bdata + (size_t)b * BUCKET_CAP;

    for (int i = t; i < NPB; i += 512) lhist[i] = 0;
    __syncthreads();
    for (int i = t; i < total; i += 512) {
        unsigned int pack = __builtin_nontemporal_load(&data[i]);
        atomicAdd(&lhist[pack >> 17], 1);             // no-return LDS atomic
    }
    __syncthreads();
    // exclusive scan lhist -> lrs (wave 0: 13 elems/lane + shfl_up wave scan)
    if (t < 64) {
        int loc[13];
        int s = 0;
#pragma unroll
        for (int k = 0; k < 13; ++k) {
            int idx = t * 13 + k;
            int v = (idx < NPB) ? lhist[idx] : 0;
            loc[k] = v; s += v;
        }
        int run = s;
#pragma unroll
        for (int off = 1; off < 64; off <<= 1) {
            int o = __shfl_up(run, off, 64);
            if (t >= off) run += o;
        }
        int excl = run - s;
#pragma unroll
        for (int k = 0; k < 13; ++k) {
            int idx = t * 13 + k;
            if (idx < NPB) lrs[idx] = excl;
            excl += loc[k];
        }
    }
    __syncthreads();
    // per-node outputs for this half (coalesced)
    const int node_lo = b * NPB + half * HALF_NPB;
    int node_hi = b * NPB + (half ? NPB : HALF_NPB);
    if (node_hi > N_NODES) node_hi = N_NODES;
    const int nn = node_hi - node_lo;
    for (int i = t; i < nn; i += 512) {
        int dloc = half * HALF_NPB + i;
        int c = lhist[dloc];
        count[node_lo + i] = c;
        row_start[node_lo + i] = bb_b + lrs[dloc];
        dinv[node_lo + i] = 1.0f / sqrtf((float)(c + 1));   // deg incl self-loop
    }
    const int slice_off = lrs[half * HALF_NPB];
    const int slice_len = half ? (total - slice_off) : lrs[HALF_NPB];
    __syncthreads();   // lhist reads done -> safe to reuse as cursors
    const int dlo = half * HALF_NPB;
    const int dhi = dlo + HALF_NPB;
    for (int i = t; i < HALF_NPB; i += 512)
        lhist[dlo + i] = lrs[dlo + i] - slice_off;    // slice-local cursors
    __syncthreads();
    for (int i = t; i < total; i += 512) {
        unsigned int pack = __builtin_nontemporal_load(&data[i]);
        int dloc = (int)(pack >> 17);
        if (dloc >= dlo && dloc < dhi) {
            int p = atomicAdd(&lhist[dloc], 1);
            if (p < SLICE_CAP)                        // defensive clamp (never expected)
                lcsr[p] = (int)(pack & 0x1FFFFu);
        }
    }
    __syncthreads();
    const int gb = bb_b + slice_off;
    for (int i = t; i < slice_len; i += 512)
        __builtin_nontemporal_store(lcsr[i], &csr_src[gb + i]);
}

// ---------------- MLP pass A: layer 1 (131 -> 64) ----------------
// REVERTED to the proven 256-thread / 32-accumulator form (70 us, R4 bench).
// The 512-thread variant compiled to a much larger VGPR allocation -> 1 block/CU
// -> 247 us. Thread half (t>>7, wave-uniform) owns 32 of 64 outputs.

__global__ __launch_bounds__(256) void k_mlp1(
        const float* __restrict__ x,
        const float* __restrict__ W1, const float* __restrict__ b1,
        float* __restrict__ h1T) {
    __shared__ float xs[TILE_NODES * KCH];   // 16896 B
    const int t = threadIdx.x;
    const int nl = t & 127;
    const int half_u = __builtin_amdgcn_readfirstlane(t >> 7);  // wave-uniform
    const int nbase = blockIdx.x * TILE_NODES;
    const int node = nbase + nl;

    float a[32];
#pragma unroll
    for (int j = 0; j < 32; ++j) a[j] = b1[half_u * 32 + j];

    for (int kc = 0; kc < 4; ++kc) {
        const int k0 = kc * KCH;
        const int len = (k0 + KCH <= 131) ? KCH : (131 - k0);   // 33,33,33,32
        __syncthreads();
        for (int i = t; i < TILE_NODES * KCH; i += 256) {
            int r = i / KCH;
            int c = i - r * KCH;
            int gr = nbase + r;
            xs[i] = (c < len && gr < N_NODES) ? x[(long)gr * 131 + k0 + c] : 0.0f;
        }
        __syncthreads();
        const float* myrow = xs + nl * KCH;
        for (int kk = 0; kk < len; ++kk) {
            float xk = myrow[kk];
            const float* wr = W1 + (k0 + kk) * 64 + half_u * 32;   // uniform -> s_load
#pragma unroll
            for (int j = 0; j < 32; ++j) a[j] += xk * wr[j];
        }
    }

    if (node < N_NODES) {
#pragma unroll
        for (int j = 0; j < 32; ++j)
            h1T[(half_u * 32 + j) * N_NODES + node] = tanhf(a[j]);
    }
}

// ---------------- MLP pass B: 64 -> 32 -> 16 -> conv-fuse ----------------
// Writes unified layout u[node*16 + j] (one 64 B line per node), dinv-scaled.

__global__ __launch_bounds__(256) void k_mlp2(
        const float* __restrict__ h1T,
        const float* __restrict__ W2, const float* __restrict__ b2,
        const float* __restrict__ W3, const float* __restrict__ b3,
        const float* __restrict__ Wc1,
        const float* __restrict__ dinv,
        float* __restrict__ up) {
    const int node = blockIdx.x * 256 + threadIdx.x;
    if (node >= N_NODES) return;

    float a2[32];
#pragma unroll
    for (int j = 0; j < 32; ++j) a2[j] = b2[j];
    for (int k = 0; k < 64; ++k) {
        float hk = h1T[k * N_NODES + node];           // coalesced
        const float* wr = W2 + k * 32;                // uniform -> s_load
#pragma unroll
        for (int j = 0; j < 32; ++j) a2[j] += hk * wr[j];
    }
#pragma unroll
    for (int j = 0; j < 32; ++j) a2[j] = tanhf(a2[j]);

    float a3[16];
#pragma unroll
    for (int j = 0; j < 16; ++j) a3[j] = b3[j];
#pragma unroll 4
    for (int k = 0; k < 32; ++k) {
        float hk = a2[k];
        const float* wr = W3 + k * 16;
#pragma unroll
        for (int j = 0; j < 16; ++j) a3[j] += hk * wr[j];
    }

    float dv = dinv[node];
    float uo[16];
#pragma unroll
    for (int j = 0; j < 16; ++j) uo[j] = 0.0f;
#pragma unroll 4
    for (int k = 0; k < 16; ++k) {
        float hk = a3[k];
        const float* wr = Wc1 + k * 16;
#pragma unroll
        for (int j = 0; j < 16; ++j) uo[j] += hk * wr[j];
    }
    float4* p = reinterpret_cast<float4*>(up + (long)node * 16);
    float4 v;
    v.x = uo[0] * dv; v.y = uo[1] * dv; v.z = uo[2] * dv; v.w = uo[3] * dv; p[0] = v;
    v.x = uo[4] * dv; v.y = uo[5] * dv; v.z = uo[6] * dv; v.w = uo[7] * dv; p[1] = v;
    v.x = uo[8] * dv; v.y = uo[9] * dv; v.z = uo[10] * dv; v.w = uo[11] * dv; p[2] = v;
    v.x = uo[12] * dv; v.y = uo[13] * dv; v.z = uo[14] * dv; v.w = uo[15] * dv; p[3] = v;
}

// ---------------- Fused aggregation + tanh + 16x16 transform (or classifier) ----------------
// One wave = 2 nodes. Per 32-lane node-group: q = lane&3 (float4 feature slot),
// g = lane>>2 & 7 (8 edge subgroups). Per 32-edge chunk each lane does
// 4 shuffles + 4 float4 gathers (16 B/lane) — 4x fewer VMEM/shfl instructions
// than the 4 B-masked-load form, same bytes. g-reduction: 3x shfl_xor on 4
// components. Epilogue folds the next layer's 16x16 W (or classifier).

__global__ __launch_bounds__(256) void k_agg(
        const float* __restrict__ u,
        const int* __restrict__ row_start,
        const int* __restrict__ count,
        const int* __restrict__ csr_src,
        const float* __restrict__ dinv,
        const float* __restrict__ bias,
        const float* __restrict__ W,      // 16x16 (mode 0) or 16x2 Wcls (mode 1)
        const float* __restrict__ bcls,   // mode 1 only
        float* __restrict__ u_next,       // mode 0 output
        float* __restrict__ out,          // mode 1 output
        int mode) {
    const int wave = threadIdx.x >> 6;
    const int lane = threadIdx.x & 63;
    const int q = lane & 3;
    const int q4 = q * 4;
    const int g = (lane >> 2) & 7;
    const int node = blockIdx.x * 8 + wave * 2 + (lane >> 5);   // 12500*8 = 100000

    const int rs = row_start[node];
    const int cnt = count[node];
    const float dv = dinv[node];
    int cmax = max(cnt, __shfl_xor(cnt, 32, 64));   // wave-uniform loop bound

    float acc[4] = {0.0f, 0.0f, 0.0f, 0.0f};
    for (int base = 0; base < cmax; base += 32) {
        int ei2 = rs + base + (lane & 31);
        if (ei2 > N_EDGES - 1) ei2 = N_EDGES - 1;    // keep csr read in bounds
        int idx = __builtin_nontemporal_load(&csr_src[ei2]);
#pragma unroll
        for (int r = 0; r < 4; ++r) {
            int e = base + 8 * r + g;
            int s = __shfl(idx, (lane & 32) + 8 * r + g, 64);
            if (e < cnt) {
                const float4 uv = *reinterpret_cast<const float4*>(u + (size_t)s * 16 + q4);
                acc[0] += uv.x; acc[1] += uv.y; acc[2] += uv.z; acc[3] += uv.w;
            }
        }
    }
    // reduce over the 8 edge subgroups (lane bits 2..4)
#pragma unroll
    for (int c = 0; c < 4; ++c) {
        acc[c] += __shfl_xor(acc[c], 4, 64);
        acc[c] += __shfl_xor(acc[c], 8, 64);
        acc[c] += __shfl_xor(acc[c], 16, 64);
    }
    // self-loop (u already dinv[src]-scaled)
    const float4 us = *reinterpret_cast<const float4*>(u + (size_t)node * 16 + q4);
    acc[0] += us.x; acc[1] += us.y; acc[2] += us.z; acc[3] += us.w;

    float hn[4];
#pragma unroll
    for (int c = 0; c < 4; ++c)
        hn[c] = tanhf(dv * acc[c] + bias[q4 + c]);

    if (mode == 0) {
        float o[4] = {0.0f, 0.0f, 0.0f, 0.0f};
#pragma unroll
        for (int k = 0; k < 16; ++k) {
            // source lane holds feature k in component k&3 (its q == k>>2, g == 0)
            float hk = __shfl(hn[k & 3], (lane & 32) + (k >> 2), 64);
            const float* wrow = W + k * 16 + q4;      // 1 KB table, L1-hot
            o[0] += hk * wrow[0]; o[1] += hk * wrow[1];
            o[2] += hk * wrow[2]; o[3] += hk * wrow[3];
        }
        if (g == 0) {
            float4 v4;
            v4.x = dv * o[0]; v4.y = dv * o[1]; v4.z = dv * o[2]; v4.w = dv * o[3];
            *reinterpret_cast<float4*>(u_next + (size_t)node * 16 + q4) = v4;
        }
    } else {
        float p0 = 0.0f, p1 = 0.0f;
        if (g == 0) {
            float4 h4; h4.x = hn[0]; h4.y = hn[1]; h4.z = hn[2]; h4.w = hn[3];
            *reinterpret_cast<float4*>(out + 200000 + (size_t)node * 16 + q4) = h4;
#pragma unroll
            for (int c = 0; c < 4; ++c) {
                p0 += hn[c] * W[(q4 + c) * 2 + 0];
                p1 += hn[c] * W[(q4 + c) * 2 + 1];
            }
        }
        p0 += __shfl_xor(p0, 1, 64);  p1 += __shfl_xor(p1, 1, 64);
        p0 += __shfl_xor(p0, 2, 64);  p1 += __shfl_xor(p1, 2, 64);
        p0 += __shfl_xor(p0, 4, 64);  p1 += __shfl_xor(p1, 4, 64);
        p0 += __shfl_xor(p0, 8, 64);  p1 += __shfl_xor(p1, 8, 64);
        p0 += __shfl_xor(p0, 16, 64); p1 += __shfl_xor(p1, 16, 64);
        if ((lane & 31) == 0) {
            out[(long)node * 2 + 0] = p0 + bcls[0];
            out[(long)node * 2 + 1] = p1 + bcls[1];
        }
    }
}

// ---------------- launch ----------------

extern "C" void kernel_launch(void* const* d_in, const int* in_sizes, int n_in,
                              void* d_out, int out_size, void* d_ws, size_t ws_size,
                              hipStream_t stream) {
    const float* x    = (const float*)d_in[0];
    const int*   ei   = (const int*)d_in[1];
    const float* W1   = (const float*)d_in[2];
    const float* b1   = (const float*)d_in[3];
    const float* W2   = (const float*)d_in[4];
    const float* b2   = (const float*)d_in[5];
    const float* W3   = (const float*)d_in[6];
    const float* b3   = (const float*)d_in[7];
    const float* Wc1  = (const float*)d_in[8];
    const float* bc1  = (const float*)d_in[9];
    const float* Wg   = (const float*)d_in[10];
    const float* bg   = (const float*)d_in[11];
    const float* Wcls = (const float*)d_in[12];
    const float* bcls = (const float*)d_in[13];
    float* out = (float*)d_out;

    const int* src = ei;
    const int* dst = ei + N_EDGES;

    int* count     = (int*)d_ws;
    int* row_start = count + N_NODES;
    float* dinv    = (float*)(row_start + N_NODES);
    int* bcnt      = (int*)(dinv + N_NODES);        // 128 ints
    int* bb        = bcnt + N_BKT;                  // 129 ints (padded to 132)
    int* csr_src   = bb + 132;
    float* u0      = (float*)(csr_src + N_EDGES);   // N*16 floats (6.4 MB), 16B-aligned
    float* u1      = u0 + 16 * N_NODES;             // N*16 floats
    float* h1T     = u1 + 16 * N_NODES;             // 64 * N floats (25.6 MB)
    unsigned int* bdata = (unsigned int*)h1T;       // 13.6 MB, dead before k_mlp1 writes h1T

    k_init<<<1, 128, 0, stream>>>(bcnt);
    k_bucket<<<BKT_NB, 256, 0, stream>>>(src, dst, bcnt, bdata);
    k_bscan<<<1, 128, 0, stream>>>(bcnt, bb);
    k_csr<<<2 * N_BKT, 512, 0, stream>>>(bdata, bcnt, bb, count, row_start, dinv, csr_src);
    k_mlp1<<<MLP1_NB, 256, 0, stream>>>(x, W1, b1, h1T);
    k_mlp2<<<SCAN_NB, 256, 0, stream>>>(h1T, W2, b2, W3, b3, Wc1, dinv, u0);

    float* ucur = u0;
    float* unxt = u1;
    for (int j = 0; j < 10; ++j) {
        const float* bias = (j < 5) ? bc1 : (bg + (long)(j - 5) * 16);
        if (j < 9) {
            const float* Wn = (j < 4) ? Wc1 : (Wg + (long)(j - 4) * 256);
            k_agg<<<12500, 256, 0, stream>>>(ucur, row_start, count, csr_src, dinv,
                                             bias, Wn, nullptr, unxt, nullptr, 0);
            float* tmp = ucur; ucur = unxt; unxt = tmp;
        } else {
            k_agg<<<12500, 256, 0, stream>>>(ucur, row_start, count, csr_src, dinv,
                                             bias, Wcls, bcls, nullptr, out, 1);
        }
    }
}